// Round 11
// baseline (4505.783 us; speedup 1.0000x reference)
//
#include <hip/hip_runtime.h>
#include <stdint.h>

#define ZB 202
#define YX 65536
#define NTOT ((size_t)ZB * YX)
#define SS 128             // pixels per superstep
#define NSS (YX / SS)      // 512 supersteps
#define PAD 4              // front slack: consumer lanes 0-2 read base+lane-3

__device__ __forceinline__ constexpr float kMU() { return 0.0009765625f; }  // 2^-10
#define MINV (-32768.0f)
#define MAXV (32767.0f)

typedef float v2f __attribute__((ext_vector_type(2)));

// global->LDS DMA, dword: per-lane GLOBAL src is arbitrary; LDS dest = uniform base + lane*4
#define GL_LDS4(g, l)                                                     \
    __builtin_amdgcn_global_load_lds(                                     \
        (const __attribute__((address_space(1))) void*)(g),               \
        (__attribute__((address_space(3))) void*)(l), 4, 0, 0)

// ---------------------------------------------------------------------------
// FULLY FUSED pipeline: one kernel, 4 blocks x 8 waves.
//
// Round-10 established: consumer scan wave is issue-bound at ~5.4 cyc/instr
// (~86 cyc/step, near its floor), and the 7 producer waves are >50% idle.
// This round folds tr_kernel + finalize_kernel + repr_kernel into the
// producers' slack and deletes the dT global round-trip:
//
//   consumer (wave 0): unchanged bit-exact recurrence; writes d to an
//     out-LDS ring via ds_write_b32 (immediate offsets -> no addr math).
//   producers (waves 1-7), per superstep ss:
//     1. issue s-reloads (asm global_load, band-coalesced) + d-column reads
//        (asm ds_read) for superstep ss-1's outputs;
//     2. DMA-stage superstep ss+1 directly from img: row t dest is
//        lane-linear [t][lane], per-lane src = img + z(lane)*YX + t
//        (z = 61b+lane-3 clamped; block 0's lanes 0-2 get junk, re-zeroed
//        after vmcnt(0) -- restores the zero-pad bands -3..-1);
//     3. vmcnt(0)+lgkmcnt(0); compute finalize outputs (IDENTICAL op
//        sequence: clamp/sub_rn/rintf/map/add_rn) + repr (=s) and store all
//        6 arrays coalesced along x.
//
// Buffer lifetimes (1 barrier/superstep): in-LDS[p] staged ss-1, read ss;
// out-LDS[p] written ss, read ss+1; both strictly 2-phase -> 2x2 buffers.
// s is re-loaded from img (not in-LDS) to avoid a 3-phase in-buffer.
//
// Consumer data path bit-exact vs rounds 3-10: in-LDS col c <-> band
// 61b+c-3; lane l reads cols {l-3..l} = {n2,n1,n0,s} (same bits -- staging
// is a bit-copy of img, zeros restored for b=0 cols 0-2); d = 3-mul +
// left-to-right 2-add; sign(s-clip(d))==sign(s-d) since |s|<32767;
// w' = fma(+-MU,n,w); d stored UNCLIPPED, clamp applied at finalize stage.
// ---------------------------------------------------------------------------
__global__ __launch_bounds__(512, 1) void scan_kernel(const float* __restrict__ img,
                                                      const float* __restrict__ w0g,
                                                      float* __restrict__ out) {
    __shared__ float ldsf[PAD + 2 * SS * 64];  // in ring:  64.02 KB
    __shared__ float ldso[2 * SS * 64];        // out ring: 64 KB

    const int tid = threadIdx.x;
    const int lane = tid & 63;
    const int wv = tid >> 6;                  // 0 = consumer, 1..7 = producers
    const int b = blockIdx.x;                 // 0..3

    float* const o_pred = out;
    float* const o_res  = out + NTOT;
    float* const o_qres = out + 2 * NTOT;
    float* const o_map  = out + 3 * NTOT;
    float* const o_repr = out + 4 * NTOT;
    float* const o_rec  = out + 5 * NTOT;

    // ---- consumer state (harmless on producers)
    const int band = 61 * b + lane - 3;
    const int wband = band < 0 ? 0 : (band > ZB - 1 ? ZB - 1 : band);
    float w0 = w0g[wband * 3 + 0];
    float w1 = w0g[wband * 3 + 1];
    float w2 = w0g[wband * 3 + 2];
    v2f Aa[16], Ab[16], Ba[16], Bb[16];
    const uint32_t inb0 =
        (uint32_t)(size_t)(__attribute__((address_space(3))) float*)(ldsf + PAD + lane - 3);
    const uint32_t otbC =
        (uint32_t)(size_t)(__attribute__((address_space(3))) float*)(ldso) + (uint32_t)(lane * 4);
    const uint32_t otbP =
        (uint32_t)(size_t)(__attribute__((address_space(3))) float*)(ldso) + (uint32_t)(lane * 256);

    // ---- producer state
    const int zcl = band < 0 ? 0 : (band > ZB - 1 ? ZB - 1 : band);  // clamped z of this lane's col
    const float* const Bz = img + (size_t)zcl * YX;
    const int cmax = (204 - 61 * b) < 63 ? (204 - 61 * b) : 63;      // last valid col (b=3: 21)

    float sA[9], sB[9], dA[9], dB[9];

    // stage superstep st into in-buf st&1: row t=r dest lane-linear, src z-strided
    auto stage = [&](int st) {
        float* lp0 = ldsf + PAD + (st & 1) * (SS * 64);
        const float* p = Bz + (size_t)st * SS;
        for (int r = wv - 1; r < SS; r += 7)
            GL_LDS4(p + r, lp0 + r * 64);
    };
    // b==0 only: restore zero-pad cols 0-2 of this wave's staged rows
    auto rezero = [&](int bn) {
        float* lp0 = ldsf + PAD + bn * (SS * 64);
        for (int r = wv - 1; r < SS; r += 7) {
            lp0[r * 64 + 0] = 0.0f; lp0[r * 64 + 1] = 0.0f; lp0[r * 64 + 2] = 0.0f;
        }
    };
    // issue superstep (Tp)'s s-reloads + d-column reads (asm: unsinkable, data after waitcnt)
    auto pissue = [&](int Tp, uint32_t pbuf) {
#pragma unroll
        for (int k = 0; k < 9; ++k) {
            const int c = 2 + wv + 7 * k;           // wave-uniform
            const int cc = c <= cmax ? c : 3;       // clamp invalid cols to a safe one
            const int zz = 61 * b + cc - 3;
            const float* sp = img + (size_t)zz * YX + Tp + lane;
            asm volatile("global_load_dword %0, %2, off\n\t"
                         "global_load_dword %1, %2, off offset:256"
                         : "=&v"(sA[k]), "=&v"(sB[k]) : "v"(sp));
            uint32_t da = otbP + pbuf + (uint32_t)(cc * 4);
            asm volatile("ds_read_b32 %0, %2\n\t"
                         "ds_read_b32 %1, %2 offset:16384"
                         : "=&v"(dA[k]), "=&v"(dB[k]) : "v"(da));
        }
    };
    // finalize outputs: IDENTICAL op sequence to the verified finalize_kernel
    auto pstore = [&](int Tp) {
#pragma unroll
        for (int k = 0; k < 9; ++k) {
            const int c = 2 + wv + 7 * k;
            if (c > cmax) continue;                 // wave-uniform branch
            const int zz = 61 * b + c - 3;
            const size_t o = (size_t)zz * YX + Tp + lane;
#pragma unroll
            for (int h = 0; h < 2; ++h) {
                const float dv = h ? dB[k] : dA[k];
                const float s = h ? sB[k] : sA[k];
                const size_t oo = o + (size_t)(h * 64);
                const float pred = fminf(fmaxf(dv, MINV), MAXV);
                const float res = __fsub_rn(s, pred);
                const int q = (int)rintf(res);
                const int m = (q >= 0) ? (2 * q) : (-2 * q - 1);
                o_pred[oo] = pred;
                o_res[oo] = res;
                o_qres[oo] = res;
                o_map[oo] = (float)m;
                o_repr[oo] = s;
                o_rec[oo] = __fadd_rn(pred, res);
            }
        }
    };

#define RTISSUE(XA, XB, cb_, st_)                                              \
    {                                                                          \
        uint32_t a0_ = inb0 + (cb_) + (uint32_t)((st_) * 4096);                \
        _Pragma("unroll") for (int k = 0; k < 16; ++k) {                       \
            uint32_t a_ = a0_ + (uint32_t)(k * 256);                           \
            asm volatile("ds_read2_b32 %0, %2 offset0:0 offset1:1\n\t"         \
                         "ds_read2_b32 %1, %2 offset0:2 offset1:3"             \
                         : "=&v"(XA[k]), "=&v"(XB[k]) : "v"(a_));              \
        }                                                                      \
    }
#define KWAIT()                                                                \
    {                                                                          \
        asm volatile("s_waitcnt lgkmcnt(0)" ::: "memory");                     \
        __builtin_amdgcn_sched_barrier(0);                                     \
    }
#define CP(BA, BB, cb_, st_)                                                   \
    {                                                                          \
        uint32_t ob_ = otbC + (cb_) + (uint32_t)((st_) * 4096);                \
        _Pragma("unroll") for (int i = 0; i < 16; ++i) {                       \
            const float nx = BA[i].x, ny = BA[i].y;                            \
            const float nz = BB[i].x, s_ = BB[i].y;                            \
            float d = __fadd_rn(                                               \
                __fadd_rn(__fmul_rn(w0, nz), __fmul_rn(w1, ny)),               \
                __fmul_rn(w2, nx));                                            \
            float sg = (s_ > d) ? kMU() : ((s_ < d) ? -kMU() : 0.0f);          \
            w0 = __builtin_fmaf(sg, nz, w0);                                   \
            w1 = __builtin_fmaf(sg, ny, w1);                                   \
            w2 = __builtin_fmaf(sg, nx, w2);                                   \
            asm volatile("ds_write_b32 %0, %1 offset:%c2"                      \
                         :: "v"(ob_), "v"(d), "i"((i) * 256) : "memory");      \
        }                                                                      \
    }

    // prologue: stage superstep 0; b0 restores zero cols after its DMAs land
    if (wv != 0) {
        stage(0);
        asm volatile("s_waitcnt vmcnt(0)" ::: "memory");
        if (b == 0) rezero(0);
    }
    __syncthreads();

    for (int ss = 0; ss < NSS; ++ss) {
        if (wv == 0) {
            const uint32_t cb = (uint32_t)((ss & 1) * 32768);
            // 8 sub-tiles of 16 steps; reads batched one sub-tile ahead (r10)
            RTISSUE(Aa, Ab, cb, 0); KWAIT();
            RTISSUE(Ba, Bb, cb, 1); CP(Aa, Ab, cb, 0); KWAIT();
            RTISSUE(Aa, Ab, cb, 2); CP(Ba, Bb, cb, 1); KWAIT();
            RTISSUE(Ba, Bb, cb, 3); CP(Aa, Ab, cb, 2); KWAIT();
            RTISSUE(Aa, Ab, cb, 4); CP(Ba, Bb, cb, 3); KWAIT();
            RTISSUE(Ba, Bb, cb, 5); CP(Aa, Ab, cb, 4); KWAIT();
            RTISSUE(Aa, Ab, cb, 6); CP(Ba, Bb, cb, 5); KWAIT();
            RTISSUE(Ba, Bb, cb, 7); CP(Aa, Ab, cb, 6); KWAIT();
            CP(Ba, Bb, cb, 7);
        } else {
            if (ss > 0) pissue((ss - 1) * SS, (uint32_t)(((ss - 1) & 1) * 32768));
            if (ss + 1 < NSS) stage(ss + 1);
            asm volatile("s_waitcnt vmcnt(0) lgkmcnt(0)" ::: "memory");
            __builtin_amdgcn_sched_barrier(0);
            if (ss > 0) pstore((ss - 1) * SS);
            if (b == 0 && ss + 1 < NSS) rezero((ss + 1) & 1);
        }
        __syncthreads();  // buffer handoff: in[ss+1] staged, out[ss] published
    }

    // epilogue: finalize the last superstep's outputs (consumer exits)
    if (wv != 0) {
        pissue((NSS - 1) * SS, (uint32_t)(((NSS - 1) & 1) * 32768));
        asm volatile("s_waitcnt vmcnt(0) lgkmcnt(0)" ::: "memory");
        __builtin_amdgcn_sched_barrier(0);
        pstore((NSS - 1) * SS);
    }

#undef RTISSUE
#undef KWAIT
#undef CP
}

extern "C" void kernel_launch(void* const* d_in, const int* in_sizes, int n_in,
                              void* d_out, int out_size, void* d_ws, size_t ws_size,
                              hipStream_t stream) {
    const float* img = (const float*)d_in[0];
    const float* w0g = (const float*)d_in[1];
    float* out = (float*)d_out;

    // Single fused kernel: scan + finalize + repr (tr/imgT/dT eliminated).
    scan_kernel<<<4, 512, 0, stream>>>(img, w0g, out);
}

// Round 12
// 2833.434 us; speedup vs baseline: 1.5902x; 1.5902x over previous
//
#include <hip/hip_runtime.h>
#include <stdint.h>

#define ZB 202
#define YX 65536
#define NTOT ((size_t)ZB * YX)
#define SS 128             // pixels per superstep
#define NSS (YX / SS)      // 512 supersteps

// LDS geometry (dwords): in [64 col][129] x2, out [128 t][65] x2, front pad
#define FPAD_DW 388        // >= 3*129 so (lane-3) col bases stay in-bounds
#define INB_DW  (64 * 129)   // 8256
#define OUTB_DW (128 * 65)   // 8320
#define IN0_B   (FPAD_DW * 4)          // 1552
#define IN1_B   (IN0_B + INB_DW * 4)   // 34576
#define OUT0_B  (IN1_B + INB_DW * 4)   // 67600
#define OUT1_B  (OUT0_B + OUTB_DW * 4) // 100880

__device__ __forceinline__ constexpr float kMU() { return 0.0009765625f; }  // 2^-10
#define MINV (-32768.0f)
#define MAXV (32767.0f)

typedef float v2f __attribute__((ext_vector_type(2)));

// global->LDS DMA, dword: per-lane global src; LDS dest = uniform base + lane*4
#define GL_LDS4(g, l)                                                     \
    __builtin_amdgcn_global_load_lds(                                     \
        (const __attribute__((address_space(1))) void*)(g),               \
        (__attribute__((address_space(3))) void*)(l), 4, 0, 0)

// ---------------------------------------------------------------------------
// FULLY FUSED pipeline: one kernel, 4 blocks x 8 waves.
//
// Round-11 post-mortem: fusion right, two producer regressions: (a) 1.6e7
// LDS bank conflicts -- d-column reads at stride 256B put all 64 lanes on one
// bank (32-way); (b) gather-DMA staging read 64 cache lines per gload_lds.
// Fix: odd-stride padded layouts, conflict-free everywhere, zero per-step
// address math:
//   in-LDS [col c][t], stride 129 dwords: staging DMA coalesced along t
//     (2x256B rows per col, the r10-proven pattern); consumer reads 2x
//     ds_read2_b32 per step, offsets {i, i+129} (stride 129 = next col,
//     same t): pair1 = {n2,n1} (cols l-3,l-2), pair2 = {n0,s} (cols l-1,l).
//     banks (129c+t) = (c+t) mod 32 -> free.
//   out-LDS [t][col], stride 65 dwords: consumer ds_write offset (t*260)
//     compile-time; banks (65t+lane) free.  Producer column read at t=lane:
//     banks (65*lane+c) free -> kills the conflicts.
//   b=0 zero-pad cols 0..2: pre-zeroed ONCE (never staged) == imgT's zeros.
//
// Consumer data path bit-exact vs all verified rounds: in col c = band
// 61b+c-3 bit-copy of img; lane l uses cols {l-3..l} = {n2,n1,n0,s};
// d = 3-mul + left-to-right 2-add; sign(s-clip(d))==sign(s-d) (|s|<32767);
// w' = fma(+-MU,n,w); d stored UNCLIPPED; finalize stage (pstore) applies
// the verified clamp/rintf/map sequence.  Dead lanes (l<3, or band>=ZB)
// write junk to out cols never finalized; junk w-walks stay lane-local.
// ---------------------------------------------------------------------------
__global__ __launch_bounds__(512, 1) void scan_kernel(const float* __restrict__ img,
                                                      const float* __restrict__ w0g,
                                                      float* __restrict__ out) {
    __shared__ float lds_all[FPAD_DW + 2 * INB_DW + 2 * OUTB_DW];  // 131.0 KB

    const int tid = threadIdx.x;
    const int lane = tid & 63;
    const int wv = tid >> 6;                  // 0 = consumer, 1..7 = producers
    const int b = blockIdx.x;                 // 0..3

    float* const o_pred = out;
    float* const o_res  = out + NTOT;
    float* const o_qres = out + 2 * NTOT;
    float* const o_map  = out + 3 * NTOT;
    float* const o_repr = out + 4 * NTOT;
    float* const o_rec  = out + 5 * NTOT;

    const uint32_t ldsb =
        (uint32_t)(size_t)(__attribute__((address_space(3))) float*)lds_all;

    // ---- consumer state (harmless on producers)
    const int band = 61 * b + lane - 3;
    const int wband = band < 0 ? 0 : (band > ZB - 1 ? ZB - 1 : band);
    float w0 = w0g[wband * 3 + 0];
    float w1 = w0g[wband * 3 + 1];
    float w2 = w0g[wband * 3 + 2];
    const uint32_t inA0 = ldsb + IN0_B + (uint32_t)((lane - 3) * 516);
    const uint32_t inA1 = inA0 + (uint32_t)(INB_DW * 4);
    const uint32_t outw0 = ldsb + OUT0_B + (uint32_t)(lane * 4);
    const uint32_t outw1 = outw0 + (uint32_t)(OUTB_DW * 4);
    v2f A1[16], A2[16], B1[16], B2[16];

    // ---- producer state
    const int cmax = (b == 3) ? 21 : 63;      // last output/staged col (band<=201)
    float sA[9], sB[9], dA[9], dB[9];

    // stage superstep st into in-buf st&1: per col, 2 coalesced 256B DMAs
    auto stage = [&](int st) {
        float* ib = lds_all + FPAD_DW + (st & 1) * INB_DW;
        const float* g0 = img + (size_t)st * SS;
        for (int c = wv - 1; c < 64; c += 7) {
            const int z = 61 * b + c - 3;
            if (z < 0 || z > ZB - 1) continue;       // b0 c<3 / b3 c>21 (uniform)
            const float* gp = g0 + (size_t)z * YX;
            float* lp = ib + c * 129;
            GL_LDS4(gp + lane, lp);
            GL_LDS4(gp + 64 + lane, lp + 64);
        }
    };
    // issue superstep Tp's s-reloads + d-column reads (asm: unsinkable)
    auto pissue = [&](int Tp, int sel) {
        const uint32_t ob = ldsb + (uint32_t)(sel ? OUT1_B : OUT0_B)
                          + (uint32_t)(lane * 260);
#pragma unroll
        for (int k = 0; k < 9; ++k) {
            const int c = 2 + wv + 7 * k;            // wave-uniform
            const int cc = c <= cmax ? c : 3;        // clamp invalid cols
            const int zz = 61 * b + cc - 3;
            const float* sp = img + (size_t)zz * YX + Tp + lane;
            asm volatile("global_load_dword %0, %2, off\n\t"
                         "global_load_dword %1, %2, off offset:256"
                         : "=&v"(sA[k]), "=&v"(sB[k]) : "v"(sp));
            const uint32_t da = ob + (uint32_t)(cc * 4);
            asm volatile("ds_read_b32 %0, %2\n\t"
                         "ds_read_b32 %1, %2 offset:16640"
                         : "=&v"(dA[k]), "=&v"(dB[k]) : "v"(da));
        }
    };
    // finalize outputs: IDENTICAL op sequence to the verified finalize path
    auto pstore = [&](int Tp) {
#pragma unroll
        for (int k = 0; k < 9; ++k) {
            const int c = 2 + wv + 7 * k;
            if (c > cmax) continue;                  // wave-uniform
            const int zz = 61 * b + c - 3;
            const size_t o = (size_t)zz * YX + Tp + lane;
#pragma unroll
            for (int h = 0; h < 2; ++h) {
                const float dv = h ? dB[k] : dA[k];
                const float s = h ? sB[k] : sA[k];
                const size_t oo = o + (size_t)(h * 64);
                const float pred = fminf(fmaxf(dv, MINV), MAXV);
                const float res = __fsub_rn(s, pred);
                const int q = (int)rintf(res);
                const int m = (q >= 0) ? (2 * q) : (-2 * q - 1);
                o_pred[oo] = pred;
                o_res[oo] = res;
                o_qres[oo] = res;
                o_map[oo] = (float)m;
                o_repr[oo] = s;
                o_rec[oo] = __fadd_rn(pred, res);
            }
        }
    };

#define RTISSUE(PA, PB, aA_)                                                   \
    {                                                                          \
        const uint32_t aB_ = (aA_) + 1032;                                     \
        _Pragma("unroll") for (int i = 0; i < 16; ++i) {                       \
            asm volatile("ds_read2_b32 %0, %1 offset0:%c2 offset1:%c3"         \
                         : "=&v"(PA[i]) : "v"(aA_), "i"(i), "i"(i + 129));     \
            asm volatile("ds_read2_b32 %0, %1 offset0:%c2 offset1:%c3"         \
                         : "=&v"(PB[i]) : "v"(aB_), "i"(i), "i"(i + 129));     \
        }                                                                      \
    }
#define KWAIT()                                                                \
    {                                                                          \
        asm volatile("s_waitcnt lgkmcnt(0)" ::: "memory");                     \
        __builtin_amdgcn_sched_barrier(0);                                     \
    }
#define CP(PA, PB, st_)                                                        \
    {                                                                          \
        _Pragma("unroll") for (int i = 0; i < 16; ++i) {                       \
            const float nx = PA[i].x, ny = PA[i].y;                            \
            const float nz = PB[i].x, s_ = PB[i].y;                            \
            float d = __fadd_rn(                                               \
                __fadd_rn(__fmul_rn(w0, nz), __fmul_rn(w1, ny)),               \
                __fmul_rn(w2, nx));                                            \
            float sg = (s_ > d) ? kMU() : ((s_ < d) ? -kMU() : 0.0f);          \
            w0 = __builtin_fmaf(sg, nz, w0);                                   \
            w1 = __builtin_fmaf(sg, ny, w1);                                   \
            w2 = __builtin_fmaf(sg, nx, w2);                                   \
            asm volatile("ds_write_b32 %0, %1 offset:%c2"                      \
                         :: "v"(outw), "v"(d),                                 \
                            "i"(((st_) * 16 + i) * 260) : "memory");           \
        }                                                                      \
    }

    // prologue: pre-zero b0's pad cols (once; never staged), stage ss 0
    if (wv != 0) {
        if (b == 0 && wv == 1) {
            for (int buf = 0; buf < 2; ++buf)
                for (int c = 0; c < 3; ++c) {
                    float* r = lds_all + FPAD_DW + buf * INB_DW + c * 129;
                    r[lane] = 0.0f;
                    r[lane + 64] = 0.0f;
                }
        }
        stage(0);
        asm volatile("s_waitcnt vmcnt(0)" ::: "memory");
    }
    __syncthreads();

    for (int ss = 0; ss < NSS; ++ss) {
        if (wv == 0) {
            const uint32_t inA = (ss & 1) ? inA1 : inA0;
            const uint32_t outw = (ss & 1) ? outw1 : outw0;
            // 8 sub-tiles of 16 steps; reads batched one sub-tile ahead
            RTISSUE(A1, A2, inA); KWAIT();
            RTISSUE(B1, B2, inA + 64);  CP(A1, A2, 0); KWAIT();
            RTISSUE(A1, A2, inA + 128); CP(B1, B2, 1); KWAIT();
            RTISSUE(B1, B2, inA + 192); CP(A1, A2, 2); KWAIT();
            RTISSUE(A1, A2, inA + 256); CP(B1, B2, 3); KWAIT();
            RTISSUE(B1, B2, inA + 320); CP(A1, A2, 4); KWAIT();
            RTISSUE(A1, A2, inA + 384); CP(B1, B2, 5); KWAIT();
            RTISSUE(B1, B2, inA + 448); CP(A1, A2, 6); KWAIT();
            CP(B1, B2, 7);
        } else {
            if (ss > 0) pissue((ss - 1) * SS, (ss - 1) & 1);
            if (ss + 1 < NSS) stage(ss + 1);
            asm volatile("s_waitcnt vmcnt(0) lgkmcnt(0)" ::: "memory");
            __builtin_amdgcn_sched_barrier(0);
            if (ss > 0) pstore((ss - 1) * SS);
        }
        __syncthreads();  // in[ss+1] staged, out[ss] published
    }

    // epilogue: finalize the last superstep's outputs
    if (wv != 0) {
        pissue((NSS - 1) * SS, (NSS - 1) & 1);
        asm volatile("s_waitcnt vmcnt(0) lgkmcnt(0)" ::: "memory");
        __builtin_amdgcn_sched_barrier(0);
        pstore((NSS - 1) * SS);
    }

#undef RTISSUE
#undef KWAIT
#undef CP
}

extern "C" void kernel_launch(void* const* d_in, const int* in_sizes, int n_in,
                              void* d_out, int out_size, void* d_ws, size_t ws_size,
                              hipStream_t stream) {
    const float* img = (const float*)d_in[0];
    const float* w0g = (const float*)d_in[1];
    float* out = (float*)d_out;

    // Single fused kernel: scan + finalize + repr.
    scan_kernel<<<4, 512, 0, stream>>>(img, w0g, out);
}

// Round 14
// 2649.986 us; speedup vs baseline: 1.7003x; 1.0692x over previous
//
#include <hip/hip_runtime.h>
#include <stdint.h>

#define ZB 202
#define YX 65536
#define NTOT ((size_t)ZB * YX)
#define SS 128             // pixels per superstep
#define NSS (YX / SS)      // 512 supersteps

// LDS geometry (dwords): in [64 col][129] x2, out [64 col][129] x2, front pad
#define FPAD_DW 388        // >= 3*129 so (lane-3) col bases stay in-bounds
#define INB_DW  (64 * 129)   // 8256
#define OUTB_DW (64 * 129)   // 8256
#define IN0_B   (FPAD_DW * 4)          // 1552
#define IN1_B   (IN0_B + INB_DW * 4)   // 34576
#define OUT0_B  (IN1_B + INB_DW * 4)   // 67600
#define OUT1_B  (OUT0_B + OUTB_DW * 4) // 100624

__device__ __forceinline__ constexpr float kMU() { return 0.0009765625f; }  // 2^-10
#define MINV (-32768.0f)
#define MAXV (32767.0f)

typedef float v2f __attribute__((ext_vector_type(2)));

// global->LDS DMA, dword: per-lane global src; LDS dest = uniform base + lane*4
#define GL_LDS4(g, l)                                                     \
    __builtin_amdgcn_global_load_lds(                                     \
        (const __attribute__((address_space(1))) void*)(g),               \
        (__attribute__((address_space(3))) void*)(l), 4, 0, 0)

// ---------------------------------------------------------------------------
// FULLY FUSED pipeline: one kernel, 4 blocks x 8 waves.
//
// Round-12 verified the conflict-free padded layouts (bank conflicts 1.6e7->0,
// kernel 4248->2582us).  Consumer remains issue-bound (~5.7 cyc/instr lone
// wave).  This round shaves issue slots, all bit-exact (r13 design, build
// bug fixed: STEP1 now uses a scoped block, no token pasting):
//   (1) v_pk_mul_f32 for the dot's two independent muls: prod = {w2,w1} x
//       {nx,ny} in ONE instr (each half is an IEEE v_mul_f32);
//       d = ((w0*nz) + prod.y) + prod.x == the verified left-to-right order.
//   (2) out-LDS re-laid as [col][129]: consumer writes d for steps (2j,2j+1)
//       with ONE ds_write2_b32 (consecutive dwords, imm offsets <= 127).
//       Banks (129*lane + t) == (lane+t): writer free, producer column read
//       (t = lane, lane+64) free.
//   Consumer: 2 reads + 4 dot + 4 sel + 3 fma + 0.5 write ~= 13.5 slots/step.
//
// Consumer data path bit-exact vs all verified rounds: in col c = band
// 61b+c-3 bit-copy of img (b0 cols 0-2 pre-zeroed once = zero-pad bands);
// lane l uses cols {l-3..l} = {n2,n1,n0,s}; d = 3-mul + left-to-right 2-add;
// sign(s-clip(d))==sign(s-d) (|s|<32767); w' = fma(+-MU,n,w); d stored
// UNCLIPPED; pstore applies the verified clamp/rintf/map sequence.
// ---------------------------------------------------------------------------
__global__ __launch_bounds__(512, 1) void scan_kernel(const float* __restrict__ img,
                                                      const float* __restrict__ w0g,
                                                      float* __restrict__ out) {
    __shared__ float lds_all[FPAD_DW + 2 * INB_DW + 2 * OUTB_DW];  // 130.5 KB

    const int tid = threadIdx.x;
    const int lane = tid & 63;
    const int wv = tid >> 6;                  // 0 = consumer, 1..7 = producers
    const int b = blockIdx.x;                 // 0..3

    float* const o_pred = out;
    float* const o_res  = out + NTOT;
    float* const o_qres = out + 2 * NTOT;
    float* const o_map  = out + 3 * NTOT;
    float* const o_repr = out + 4 * NTOT;
    float* const o_rec  = out + 5 * NTOT;

    const uint32_t ldsb =
        (uint32_t)(size_t)(__attribute__((address_space(3))) float*)lds_all;

    // ---- consumer state (harmless on producers)
    const int band = 61 * b + lane - 3;
    const int wband = band < 0 ? 0 : (band > ZB - 1 ? ZB - 1 : band);
    float w0 = w0g[wband * 3 + 0];
    v2f W21;                                   // {w2, w1} packed pair
    W21.x = w0g[wband * 3 + 2];
    W21.y = w0g[wband * 3 + 1];
    const uint32_t inA0 = ldsb + IN0_B + (uint32_t)((lane - 3) * 516);
    const uint32_t inA1 = inA0 + (uint32_t)(INB_DW * 4);
    const uint32_t outw0 = ldsb + OUT0_B + (uint32_t)(lane * 516);  // col=lane base
    const uint32_t outw1 = outw0 + (uint32_t)(OUTB_DW * 4);
    v2f A1[16], A2[16], B1[16], B2[16];

    // ---- producer state
    const int cmax = (b == 3) ? 21 : 63;      // last output/staged col (band<=201)
    float sA[9], sB[9], dA[9], dB[9];

    // stage superstep st into in-buf st&1: per col, 2 coalesced 256B DMAs
    auto stage = [&](int st) {
        float* ib = lds_all + FPAD_DW + (st & 1) * INB_DW;
        const float* g0 = img + (size_t)st * SS;
        for (int c = wv - 1; c < 64; c += 7) {
            const int z = 61 * b + c - 3;
            if (z < 0 || z > ZB - 1) continue;       // b0 c<3 / b3 c>21 (uniform)
            const float* gp = g0 + (size_t)z * YX;
            float* lp = ib + c * 129;
            GL_LDS4(gp + lane, lp);
            GL_LDS4(gp + 64 + lane, lp + 64);
        }
    };
    // issue superstep Tp's s-reloads + d-column reads (asm: unsinkable)
    auto pissue = [&](int Tp, int sel) {
        const uint32_t ob = ldsb + (uint32_t)(sel ? OUT1_B : OUT0_B)
                          + (uint32_t)(lane * 4);     // t = lane within a col
#pragma unroll
        for (int k = 0; k < 9; ++k) {
            const int c = 2 + wv + 7 * k;            // wave-uniform
            const int cc = c <= cmax ? c : 3;        // clamp invalid cols
            const int zz = 61 * b + cc - 3;
            const float* sp = img + (size_t)zz * YX + Tp + lane;
            asm volatile("global_load_dword %0, %2, off\n\t"
                         "global_load_dword %1, %2, off offset:256"
                         : "=&v"(sA[k]), "=&v"(sB[k]) : "v"(sp));
            const uint32_t da = ob + (uint32_t)(cc * 516);   // col cc, t=lane
            asm volatile("ds_read_b32 %0, %2\n\t"
                         "ds_read_b32 %1, %2 offset:256"      // t = lane+64
                         : "=&v"(dA[k]), "=&v"(dB[k]) : "v"(da));
        }
    };
    // finalize outputs: IDENTICAL op sequence to the verified finalize path
    auto pstore = [&](int Tp) {
#pragma unroll
        for (int k = 0; k < 9; ++k) {
            const int c = 2 + wv + 7 * k;
            if (c > cmax) continue;                  // wave-uniform
            const int zz = 61 * b + c - 3;
            const size_t o = (size_t)zz * YX + Tp + lane;
#pragma unroll
            for (int h = 0; h < 2; ++h) {
                const float dv = h ? dB[k] : dA[k];
                const float s = h ? sB[k] : sA[k];
                const size_t oo = o + (size_t)(h * 64);
                const float pred = fminf(fmaxf(dv, MINV), MAXV);
                const float res = __fsub_rn(s, pred);
                const int q = (int)rintf(res);
                const int m = (q >= 0) ? (2 * q) : (-2 * q - 1);
                o_pred[oo] = pred;
                o_res[oo] = res;
                o_qres[oo] = res;
                o_map[oo] = (float)m;
                o_repr[oo] = s;
                o_rec[oo] = __fadd_rn(pred, res);
            }
        }
    };

#define RTISSUE(PA, PB, aA_)                                                   \
    {                                                                          \
        const uint32_t aB_ = (aA_) + 1032;                                     \
        _Pragma("unroll") for (int i = 0; i < 16; ++i) {                       \
            asm volatile("ds_read2_b32 %0, %1 offset0:%c2 offset1:%c3"         \
                         : "=&v"(PA[i]) : "v"(aA_), "i"(i), "i"(i + 129));     \
            asm volatile("ds_read2_b32 %0, %1 offset0:%c2 offset1:%c3"         \
                         : "=&v"(PB[i]) : "v"(aB_), "i"(i), "i"(i + 129));     \
        }                                                                      \
    }
#define KWAIT()                                                                \
    {                                                                          \
        asm volatile("s_waitcnt lgkmcnt(0)" ::: "memory");                     \
        __builtin_amdgcn_sched_barrier(0);                                     \
    }
// one recurrence step (bit-exact; pk_mul halves == the two independent muls);
// scoped block, no token pasting; result returned via dres_ (declared by caller)
#define STEP1(PA, PB, i_, dres_)                                               \
    {                                                                          \
        const float nz_ = PB[i_].x, s_ = PB[i_].y;                             \
        v2f pr_;                                                               \
        asm("v_pk_mul_f32 %0, %1, %2" : "=v"(pr_) : "v"(W21), "v"(PA[i_]));    \
        dres_ = __fadd_rn(__fadd_rn(__fmul_rn(w0, nz_), pr_.y), pr_.x);        \
        const float sg = (s_ > dres_) ? kMU()                                  \
                         : ((s_ < dres_) ? -kMU() : 0.0f);                     \
        w0 = __builtin_fmaf(sg, nz_, w0);                                      \
        W21.y = __builtin_fmaf(sg, PA[i_].y, W21.y);                           \
        W21.x = __builtin_fmaf(sg, PA[i_].x, W21.x);                           \
    }
#define CP(PA, PB, st_)                                                        \
    {                                                                          \
        _Pragma("unroll") for (int j = 0; j < 8; ++j) {                        \
            float d0_, d1_;                                                    \
            STEP1(PA, PB, (2 * j), d0_);                                       \
            STEP1(PA, PB, (2 * j + 1), d1_);                                   \
            asm volatile("ds_write2_b32 %0, %1, %2 offset0:%c3 offset1:%c4"    \
                         :: "v"(outw), "v"(d0_), "v"(d1_),                     \
                            "i"((st_) * 16 + 2 * j),                           \
                            "i"((st_) * 16 + 2 * j + 1) : "memory");           \
        }                                                                      \
    }

    // prologue: pre-zero b0's pad cols (once; never staged), stage ss 0
    if (wv != 0) {
        if (b == 0 && wv == 1) {
            for (int buf = 0; buf < 2; ++buf)
                for (int c = 0; c < 3; ++c) {
                    float* r = lds_all + FPAD_DW + buf * INB_DW + c * 129;
                    r[lane] = 0.0f;
                    r[lane + 64] = 0.0f;
                }
        }
        stage(0);
        asm volatile("s_waitcnt vmcnt(0)" ::: "memory");
    }
    __syncthreads();

    for (int ss = 0; ss < NSS; ++ss) {
        if (wv == 0) {
            const uint32_t inA = (ss & 1) ? inA1 : inA0;
            const uint32_t outw = (ss & 1) ? outw1 : outw0;
            // 8 sub-tiles of 16 steps; reads batched one sub-tile ahead
            RTISSUE(A1, A2, inA); KWAIT();
            RTISSUE(B1, B2, inA + 64);  CP(A1, A2, 0); KWAIT();
            RTISSUE(A1, A2, inA + 128); CP(B1, B2, 1); KWAIT();
            RTISSUE(B1, B2, inA + 192); CP(A1, A2, 2); KWAIT();
            RTISSUE(A1, A2, inA + 256); CP(B1, B2, 3); KWAIT();
            RTISSUE(B1, B2, inA + 320); CP(A1, A2, 4); KWAIT();
            RTISSUE(A1, A2, inA + 384); CP(B1, B2, 5); KWAIT();
            RTISSUE(B1, B2, inA + 448); CP(A1, A2, 6); KWAIT();
            CP(B1, B2, 7);
        } else {
            if (ss > 0) pissue((ss - 1) * SS, (ss - 1) & 1);
            if (ss + 1 < NSS) stage(ss + 1);
            asm volatile("s_waitcnt vmcnt(0) lgkmcnt(0)" ::: "memory");
            __builtin_amdgcn_sched_barrier(0);
            if (ss > 0) pstore((ss - 1) * SS);
        }
        __syncthreads();  // in[ss+1] staged, out[ss] published
    }

    // epilogue: finalize the last superstep's outputs
    if (wv != 0) {
        pissue((NSS - 1) * SS, (NSS - 1) & 1);
        asm volatile("s_waitcnt vmcnt(0) lgkmcnt(0)" ::: "memory");
        __builtin_amdgcn_sched_barrier(0);
        pstore((NSS - 1) * SS);
    }

#undef RTISSUE
#undef KWAIT
#undef STEP1
#undef CP
}

extern "C" void kernel_launch(void* const* d_in, const int* in_sizes, int n_in,
                              void* d_out, int out_size, void* d_ws, size_t ws_size,
                              hipStream_t stream) {
    const float* img = (const float*)d_in[0];
    const float* w0g = (const float*)d_in[1];
    float* out = (float*)d_out;

    // Single fused kernel: scan + finalize + repr.
    scan_kernel<<<4, 512, 0, stream>>>(img, w0g, out);
}